// Round 1
// baseline (1109.818 us; speedup 1.0000x reference)
//
#include <hip/hip_runtime.h>
#include <cstdint>
#include <cstddef>

#define E_TOT 131072
#define NNODES 8192

typedef __attribute__((ext_vector_type(8))) short bf16x8;
typedef __attribute__((ext_vector_type(4))) float f32x4;
typedef unsigned short u16;
typedef unsigned int u32;

__device__ __forceinline__ u16 f2bf(float f) {
    u32 u = __builtin_bit_cast(u32, f);
    u32 r = (u + 0x7FFFu + ((u >> 16) & 1u)) >> 16;
    return (u16)r;
}

// ---- weight convert + transpose: dst[n*K+k] = bf16(src[k*N+n]) ----
__global__ void wconv_kernel(const float* __restrict__ src, u16* __restrict__ dst,
                             int K, int N) {
    int idx = blockIdx.x * 256 + threadIdx.x;
    if (idx >= N * K) return;
    int n = idx / K, k = idx - n * K;
    dst[idx] = f2bf(src[(size_t)k * N + n]);
}

// ---- x f32 -> bf16 ----
__global__ void xconv_kernel(const float4* __restrict__ x, ushort4* __restrict__ xb) {
    size_t i = (size_t)blockIdx.x * 256 + threadIdx.x;
    float4 v = x[i];
    ushort4 o;
    o.x = f2bf(v.x); o.y = f2bf(v.y); o.z = f2bf(v.z); o.w = f2bf(v.w);
    xb[i] = o;
}

// ---- envelope(r) and Y = [1, sqrt3*nhat] per edge ----
__global__ void envy_kernel(const float* __restrict__ vectors, float* __restrict__ env,
                            float4* __restrict__ Y) {
    int e = blockIdx.x * 256 + threadIdx.x;
    float vx = vectors[3 * e + 0], vy = vectors[3 * e + 1], vz = vectors[3 * e + 2];
    float r2 = vx * vx + vy * vy + vz * vz;
    float r = sqrtf(r2);
    float u6 = r2 * r2 * r2;
    float f = 1.0f + u6 * (-28.0f + 48.0f * r - 21.0f * r2);
    env[e] = (r < 1.0f) ? f : 0.0f;
    float inv = 1.7320508075688772f / r;
    Y[e] = make_float4(1.0f, vx * inv, vy * inv, vz * inv);
}

// ---- w = x @ W_w / sqrt(512): M=E, N=64, K=512, tile 128x64xBK64 ----
__launch_bounds__(256)
__global__ void wgemm_kernel(const u16* __restrict__ XB, const u16* __restrict__ Wt,
                             float* __restrict__ w) {
    __shared__ u16 As[128 * 72];
    __shared__ u16 Bs[64 * 72];
    const int e0 = blockIdx.x * 128;
    const int t = threadIdx.x, lane = t & 63, wid = t >> 6;
    const int lr = lane & 15, lh = lane >> 4;
    const int r8 = t >> 3, c8 = t & 7;
    f32x4 acc[2][4] = {};
    for (int kt = 0; kt < 8; ++kt) {
        const int kk = kt << 6;
#pragma unroll
        for (int i = 0; i < 4; ++i) {
            int row = i * 32 + r8;
            const u16* g = XB + (size_t)(e0 + row) * 512 + kk + c8 * 8;
            *(uint4*)((char*)As + row * 144 + c8 * 16) = *(const uint4*)g;
        }
#pragma unroll
        for (int i = 0; i < 2; ++i) {
            int row = i * 32 + r8;
            const u16* g = Wt + (size_t)row * 512 + kk + c8 * 8;
            *(uint4*)((char*)Bs + row * 144 + c8 * 16) = *(const uint4*)g;
        }
        __syncthreads();
#pragma unroll
        for (int k2 = 0; k2 < 2; ++k2) {
            bf16x8 af[2], bfr[4];
#pragma unroll
            for (int m = 0; m < 2; ++m)
                af[m] = *(const bf16x8*)((const char*)As + (wid * 32 + m * 16 + lr) * 144 + k2 * 64 + lh * 16);
#pragma unroll
            for (int n = 0; n < 4; ++n)
                bfr[n] = *(const bf16x8*)((const char*)Bs + (n * 16 + lr) * 144 + k2 * 64 + lh * 16);
#pragma unroll
            for (int m = 0; m < 2; ++m)
#pragma unroll
                for (int n = 0; n < 4; ++n)
                    acc[m][n] = __builtin_amdgcn_mfma_f32_16x16x32_bf16(af[m], bfr[n], acc[m][n], 0, 0, 0);
        }
        __syncthreads();
    }
    const float s = 0.044194173824159216f; // 1/sqrt(512)
#pragma unroll
    for (int m = 0; m < 2; ++m)
#pragma unroll
        for (int n = 0; n < 4; ++n)
#pragma unroll
            for (int j = 0; j < 4; ++j) {
                int e = e0 + wid * 32 + m * 16 + lh * 4 + j;
                w[(size_t)e * 64 + n * 16 + lr] = acc[m][n][j] * s;
            }
}

// ---- scatter: agg[s][m][c] += w[e][m] * Y[e][c] ----
__global__ void scatter_kernel(const float* __restrict__ w, const int* __restrict__ senders,
                               const float4* __restrict__ Y, float* __restrict__ agg) {
    int idx = blockIdx.x * 256 + threadIdx.x; // over E*64
    int e = idx >> 6, m = idx & 63;
    float wv = w[idx];
    int s = senders[e];
    float4 y = Y[e];
    float* p = agg + ((size_t)s * 64 + m) * 4;
    unsafeAtomicAdd(p + 0, wv * y.x);
    unsafeAtomicAdd(p + 1, wv * y.y);
    unsafeAtomicAdd(p + 2, wv * y.z);
    unsafeAtomicAdd(p + 3, wv * y.w);
}

// ---- edge products: scal (bf16) + fused V_out GEMM (K=192) ----
// block = 32 edges, 256 threads (4 waves)
__launch_bounds__(256)
__global__ void edge_kernel(const int* __restrict__ senders, const float4* __restrict__ agg4,
                            const float4* __restrict__ V4, const u16* __restrict__ Wlt,
                            u16* __restrict__ scal, float* __restrict__ Vout) {
    __shared__ u16 a_lds[3][32][200];
    __shared__ u16 w_lds[64 * 200];
    const int t = threadIdx.x;
    const int e0 = blockIdx.x * 32;
    // stage W_lin^T [64][192] into padded LDS [64][200]
#pragma unroll
    for (int i = 0; i < 6; ++i) {
        int c = i * 256 + t; // 1536 chunks of 8 u16
        int row = c / 24, off = (c % 24) * 8;
        *(uint4*)((char*)w_lds + row * 400 + off * 2) = ((const uint4*)Wlt)[c];
    }
    const float invs3 = 0.5773502691896258f;
    const float invs2 = 0.7071067811865476f;
    const float EPS = 0.24253562503633297f;
#pragma unroll
    for (int i = 0; i < 8; ++i) {
        int el = i * 4 + (t >> 6);
        int m = t & 63;
        int e = e0 + el;
        int s = senders[e];
        float4 a = agg4[(size_t)s * 64 + m];
        a.x *= EPS; a.y *= EPS; a.z *= EPS; a.w *= EPS;
        float4 b = V4[(size_t)e * 64 + m];
        float s0 = a.x * b.x;
        float s1 = (a.y * b.y + a.z * b.z + a.w * b.w) * invs3;
        scal[(size_t)e * 128 + m] = f2bf(s0);
        scal[(size_t)e * 128 + 64 + m] = f2bf(s1);
        float cx = (a.z * b.w - a.w * b.z) * invs2;
        float cy = (a.w * b.y - a.y * b.w) * invs2;
        float cz = (a.y * b.z - a.z * b.y) * invs2;
        a_lds[0][el][m] = f2bf(a.x * b.y);
        a_lds[0][el][64 + m] = f2bf(a.y * b.x);
        a_lds[0][el][128 + m] = f2bf(cx);
        a_lds[1][el][m] = f2bf(a.x * b.z);
        a_lds[1][el][64 + m] = f2bf(a.z * b.x);
        a_lds[1][el][128 + m] = f2bf(cy);
        a_lds[2][el][m] = f2bf(a.x * b.w);
        a_lds[2][el][64 + m] = f2bf(a.w * b.x);
        a_lds[2][el][128 + m] = f2bf(cz);
    }
    __syncthreads();
    const int lane = t & 63, wid = t >> 6;
    const int lr = lane & 15, lh = lane >> 4;
    f32x4 acc[3][2] = {};
    for (int kt = 0; kt < 6; ++kt) {
        bf16x8 bfr = *(const bf16x8*)((const char*)w_lds + (wid * 16 + lr) * 400 + kt * 64 + lh * 16);
#pragma unroll
        for (int c = 0; c < 3; ++c)
#pragma unroll
            for (int m = 0; m < 2; ++m) {
                bf16x8 afr = *(const bf16x8*)((const char*)a_lds + ((c * 32 + m * 16 + lr) * 400) + kt * 64 + lh * 16);
                acc[c][m] = __builtin_amdgcn_mfma_f32_16x16x32_bf16(afr, bfr, acc[c][m], 0, 0, 0);
            }
    }
    __syncthreads();
    float* ot = (float*)a_lds; // reuse as [32][192] f32 out tile
    const float sc = 0.07216878364870323f; // 1/sqrt(192)
#pragma unroll
    for (int c = 0; c < 3; ++c)
#pragma unroll
        for (int m = 0; m < 2; ++m)
#pragma unroll
            for (int j = 0; j < 4; ++j) {
                int row = m * 16 + lh * 4 + j;
                int mul = wid * 16 + lr;
                ot[row * 192 + mul * 3 + c] = acc[c][m][j] * sc;
            }
    __syncthreads();
    float4* vo = (float4*)(Vout + (size_t)e0 * 192);
#pragma unroll
    for (int i = 0; i < 6; ++i)
        vo[i * 256 + t] = ((float4*)ot)[i * 256 + t];
}

// ---- MLP GEMM 128x128xBK64, MODE 0: silu->bf16, MODE 1: env-scale->f32 ----
template <int MODE>
__launch_bounds__(256)
__global__ void mlp_gemm(const u16* __restrict__ A, const u16* __restrict__ A2,
                         const u16* __restrict__ Bt, const int K, const float scale,
                         const float* __restrict__ env,
                         u16* __restrict__ outb, float* __restrict__ outf) {
    __shared__ u16 As[128 * 72];
    __shared__ u16 Bs[128 * 72];
    const int bid = blockIdx.x;
    const int mt = bid >> 2, nt = bid & 3;
    const int e0 = mt << 7, n0 = nt << 7;
    const int t = threadIdx.x, lane = t & 63, wid = t >> 6;
    const int wm = wid & 1, wn = wid >> 1;
    const int lr = lane & 15, lh = lane >> 4;
    const int r8 = t >> 3, c8 = t & 7;
    f32x4 acc[4][4] = {};
    const int nkt = K >> 6;
    for (int kt = 0; kt < nkt; ++kt) {
        const int kk = kt << 6;
#pragma unroll
        for (int i = 0; i < 4; ++i) {
            const int row = i * 32 + r8;
            const u16* g;
            if (A2 && kk >= 512) g = A2 + (size_t)(e0 + row) * 128 + (kk - 512) + c8 * 8;
            else                 g = A + (size_t)(e0 + row) * 512 + kk + c8 * 8;
            *(uint4*)((char*)As + row * 144 + c8 * 16) = *(const uint4*)g;
        }
#pragma unroll
        for (int i = 0; i < 4; ++i) {
            const int row = i * 32 + r8;
            const u16* g = Bt + (size_t)(n0 + row) * K + kk + c8 * 8;
            *(uint4*)((char*)Bs + row * 144 + c8 * 16) = *(const uint4*)g;
        }
        __syncthreads();
#pragma unroll
        for (int k2 = 0; k2 < 2; ++k2) {
            bf16x8 af[4], bfr[4];
#pragma unroll
            for (int m = 0; m < 4; ++m)
                af[m] = *(const bf16x8*)((const char*)As + (wm * 64 + m * 16 + lr) * 144 + k2 * 64 + lh * 16);
#pragma unroll
            for (int n = 0; n < 4; ++n)
                bfr[n] = *(const bf16x8*)((const char*)Bs + (wn * 64 + n * 16 + lr) * 144 + k2 * 64 + lh * 16);
#pragma unroll
            for (int m = 0; m < 4; ++m)
#pragma unroll
                for (int n = 0; n < 4; ++n)
                    acc[m][n] = __builtin_amdgcn_mfma_f32_16x16x32_bf16(af[m], bfr[n], acc[m][n], 0, 0, 0);
        }
        __syncthreads();
    }
#pragma unroll
    for (int m = 0; m < 4; ++m) {
#pragma unroll
        for (int j = 0; j < 4; ++j) {
            const int row = e0 + wm * 64 + m * 16 + lh * 4 + j;
            float ev = (MODE == 1) ? env[row] : 0.0f;
#pragma unroll
            for (int n = 0; n < 4; ++n) {
                const int col = n0 + wn * 64 + n * 16 + lr;
                float v = acc[m][n][j] * scale;
                if (MODE == 0) {
                    float sv = v / (1.0f + __expf(-v));
                    outb[(size_t)row * 512 + col] = f2bf(sv);
                } else {
                    outf[(size_t)row * 512 + col] = v * ev;
                }
            }
        }
    }
}

extern "C" void kernel_launch(void* const* d_in, const int* in_sizes, int n_in,
                              void* d_out, int out_size, void* d_ws, size_t ws_size,
                              hipStream_t stream) {
    const float* vectors = (const float*)d_in[0];
    const float* x       = (const float*)d_in[1];
    const float* V       = (const float*)d_in[2];
    const int*   senders = (const int*)d_in[3];
    const float* W_w     = (const float*)d_in[4];
    const float* W1      = (const float*)d_in[5];
    const float* W2      = (const float*)d_in[6];
    const float* W3      = (const float*)d_in[7];
    const float* W_lin   = (const float*)d_in[8];
    float* out = (float*)d_out;
    char* ws = (char*)d_ws;

    u16*    XB   = (u16*)(ws + 0x0);         // E*512 bf16
    u16*    H1   = (u16*)(ws + 0x8000000);   // E*512 bf16
    u16*    SCAL = (u16*)(ws + 0x10000000);  // E*128 bf16
    float*  AGG  = (float*)(ws + 0x12000000);// 8192*256 f32
    float*  ENV  = (float*)(ws + 0x12800000);// E f32
    float4* Yb   = (float4*)(ws + 0x12880000);// E float4
    float*  Wbuf = (float*)(ws + 0x12A80000);// E*64 f32
    u16*    WT   = (u16*)(ws + 0x14A80000);  // weights bf16
    u16* Wwt = WT;                 // 64 x 512
    u16* W1t = Wwt + 64 * 512;     // 512 x 640
    u16* W2t = W1t + 512 * 640;    // 512 x 512
    u16* W3t = W2t + 512 * 512;    // 512 x 512
    u16* Wlt = W3t + 512 * 512;    // 64 x 192
    u16* H2 = XB;                  // reuse XB for h2

    hipMemsetAsync(AGG, 0, (size_t)NNODES * 256 * 4, stream);

    wconv_kernel<<<(64 * 512) / 256, 256, 0, stream>>>(W_w, Wwt, 512, 64);
    wconv_kernel<<<(512 * 640) / 256, 256, 0, stream>>>(W1, W1t, 640, 512);
    wconv_kernel<<<(512 * 512) / 256, 256, 0, stream>>>(W2, W2t, 512, 512);
    wconv_kernel<<<(512 * 512) / 256, 256, 0, stream>>>(W3, W3t, 512, 512);
    wconv_kernel<<<(64 * 192) / 256, 256, 0, stream>>>(W_lin, Wlt, 192, 64);

    xconv_kernel<<<(E_TOT * 512 / 4) / 256, 256, 0, stream>>>((const float4*)x, (ushort4*)XB);
    envy_kernel<<<E_TOT / 256, 256, 0, stream>>>(vectors, ENV, Yb);

    wgemm_kernel<<<E_TOT / 128, 256, 0, stream>>>(XB, Wwt, Wbuf);
    scatter_kernel<<<(E_TOT * 64) / 256, 256, 0, stream>>>(Wbuf, senders, Yb, AGG);

    edge_kernel<<<E_TOT / 32, 256, 0, stream>>>(senders, (const float4*)AGG, (const float4*)V,
                                                Wlt, SCAL, out + (size_t)E_TOT * 512);

    const float s640 = 0.03952847075210474f;  // 1/sqrt(640)
    const float s512 = 0.044194173824159216f; // 1/sqrt(512)
    mlp_gemm<0><<<(E_TOT / 128) * 4, 256, 0, stream>>>(XB, SCAL, W1t, 640, s640, nullptr, H1, nullptr);
    mlp_gemm<0><<<(E_TOT / 128) * 4, 256, 0, stream>>>(H1, nullptr, W2t, 512, s512, nullptr, H2, nullptr);
    mlp_gemm<1><<<(E_TOT / 128) * 4, 256, 0, stream>>>(H2, nullptr, W3t, 512, s512, ENV, nullptr, out);
}

// Round 2
// 727.599 us; speedup vs baseline: 1.5253x; 1.5253x over previous
//
#include <hip/hip_runtime.h>
#include <cstdint>
#include <cstddef>

#define E_TOT 131072
#define NNODES 8192

typedef __attribute__((ext_vector_type(8))) short bf16x8;
typedef __attribute__((ext_vector_type(4))) float f32x4;
typedef unsigned short u16;
typedef unsigned int u32;

__device__ __forceinline__ u16 f2bf(float f) {
    u32 u = __builtin_bit_cast(u32, f);
    u32 r = (u + 0x7FFFu + ((u >> 16) & 1u)) >> 16;
    return (u16)r;
}

__device__ __forceinline__ void gload16(const u16* g, u16* l) {
    __builtin_amdgcn_global_load_lds((const __attribute__((address_space(1))) void*)g,
                                     (__attribute__((address_space(3))) void*)l, 16, 0, 0);
}

// ---- weight convert + transpose: dst[n*K+k] = bf16(src[k*N+n]) ----
__global__ void wconv_kernel(const float* __restrict__ src, u16* __restrict__ dst,
                             int K, int N) {
    int idx = blockIdx.x * 256 + threadIdx.x;
    if (idx >= N * K) return;
    int n = idx / K, k = idx - n * K;
    dst[idx] = f2bf(src[(size_t)k * N + n]);
}

// ---- x f32 -> bf16 ----
__global__ void xconv_kernel(const float4* __restrict__ x, ushort4* __restrict__ xb) {
    size_t i = (size_t)blockIdx.x * 256 + threadIdx.x;
    float4 v = x[i];
    ushort4 o;
    o.x = f2bf(v.x); o.y = f2bf(v.y); o.z = f2bf(v.z); o.w = f2bf(v.w);
    xb[i] = o;
}

// ---- envelope(r) and Y = [1, sqrt3*nhat] per edge ----
__global__ void envy_kernel(const float* __restrict__ vectors, float* __restrict__ env,
                            float4* __restrict__ Y) {
    int e = blockIdx.x * 256 + threadIdx.x;
    float vx = vectors[3 * e + 0], vy = vectors[3 * e + 1], vz = vectors[3 * e + 2];
    float r2 = vx * vx + vy * vy + vz * vz;
    float r = sqrtf(r2);
    float u6 = r2 * r2 * r2;
    float f = 1.0f + u6 * (-28.0f + 48.0f * r - 21.0f * r2);
    env[e] = (r < 1.0f) ? f : 0.0f;
    float inv = 1.7320508075688772f / r;
    Y[e] = make_float4(1.0f, vx * inv, vy * inv, vz * inv);
}

// ---- counting sort: histogram ----
__global__ void hist_kernel(const int* __restrict__ senders, int* __restrict__ cnt) {
    int e = blockIdx.x * 256 + threadIdx.x;
    atomicAdd(&cnt[senders[e]], 1);
}

// ---- single-block exclusive scan of 8192 counts -> off[8193], curs[8192] ----
__launch_bounds__(1024)
__global__ void scan_kernel(const int* __restrict__ cnt, int* __restrict__ off,
                            int* __restrict__ curs) {
    __shared__ int part[1024];
    const int t = threadIdx.x;
    int local[8];
    int s = 0;
#pragma unroll
    for (int j = 0; j < 8; ++j) { local[j] = cnt[t * 8 + j]; s += local[j]; }
    part[t] = s;
    __syncthreads();
    for (int d = 1; d < 1024; d <<= 1) {
        int v = (t >= d) ? part[t - d] : 0;
        __syncthreads();
        part[t] += v;
        __syncthreads();
    }
    int run = part[t] - s; // exclusive base
#pragma unroll
    for (int j = 0; j < 8; ++j) {
        off[t * 8 + j] = run;
        curs[t * 8 + j] = run;
        run += local[j];
    }
    if (t == 1023) off[8192] = run;
}

// ---- perm build: perm[pos] = e ----
__global__ void permbuild_kernel(const int* __restrict__ senders, int* __restrict__ curs,
                                 int* __restrict__ perm) {
    int e = blockIdx.x * 256 + threadIdx.x;
    int s = senders[e];
    int p = atomicAdd(&curs[s], 1);
    perm[p] = e;
}

// ---- gather segment-sum: agg[n][m][:] = sum_{e in seg(n)} w[e][m]*Y[e] ----
__launch_bounds__(256)
__global__ void gather_kernel(const float* __restrict__ w, const float4* __restrict__ Y,
                              const int* __restrict__ off, const int* __restrict__ perm,
                              float4* __restrict__ agg) {
    const int t = threadIdx.x;
    const int n = blockIdx.x * 4 + (t >> 6);
    const int m = t & 63;
    const int beg = off[n], end = off[n + 1];
    float4 acc = make_float4(0.f, 0.f, 0.f, 0.f);
    for (int i = beg; i < end; ++i) {
        int e = perm[i];
        float wv = w[(size_t)e * 64 + m];
        float4 y = Y[e];
        acc.x += wv * y.x; acc.y += wv * y.y; acc.z += wv * y.z; acc.w += wv * y.w;
    }
    agg[(size_t)n * 64 + m] = acc;
}

// ---- w = x @ W_w / sqrt(512): M=E, N=64, K=512, tile 128x64xBK64 ----
__launch_bounds__(256)
__global__ void wgemm_kernel(const u16* __restrict__ XB, const u16* __restrict__ Wt,
                             float* __restrict__ w) {
    __shared__ u16 As[128 * 72];
    __shared__ u16 Bs[64 * 72];
    const int e0 = blockIdx.x * 128;
    const int t = threadIdx.x, lane = t & 63, wid = t >> 6;
    const int lr = lane & 15, lh = lane >> 4;
    const int r8 = t >> 3, c8 = t & 7;
    f32x4 acc[2][4] = {};
    for (int kt = 0; kt < 8; ++kt) {
        const int kk = kt << 6;
#pragma unroll
        for (int i = 0; i < 4; ++i) {
            int row = i * 32 + r8;
            const u16* g = XB + (size_t)(e0 + row) * 512 + kk + c8 * 8;
            *(uint4*)((char*)As + row * 144 + c8 * 16) = *(const uint4*)g;
        }
#pragma unroll
        for (int i = 0; i < 2; ++i) {
            int row = i * 32 + r8;
            const u16* g = Wt + (size_t)row * 512 + kk + c8 * 8;
            *(uint4*)((char*)Bs + row * 144 + c8 * 16) = *(const uint4*)g;
        }
        __syncthreads();
#pragma unroll
        for (int k2 = 0; k2 < 2; ++k2) {
            bf16x8 af[2], bfr[4];
#pragma unroll
            for (int m = 0; m < 2; ++m)
                af[m] = *(const bf16x8*)((const char*)As + (wid * 32 + m * 16 + lr) * 144 + k2 * 64 + lh * 16);
#pragma unroll
            for (int n = 0; n < 4; ++n)
                bfr[n] = *(const bf16x8*)((const char*)Bs + (n * 16 + lr) * 144 + k2 * 64 + lh * 16);
#pragma unroll
            for (int m = 0; m < 2; ++m)
#pragma unroll
                for (int n = 0; n < 4; ++n)
                    acc[m][n] = __builtin_amdgcn_mfma_f32_16x16x32_bf16(af[m], bfr[n], acc[m][n], 0, 0, 0);
        }
        __syncthreads();
    }
    const float s = 0.044194173824159216f; // 1/sqrt(512)
#pragma unroll
    for (int m = 0; m < 2; ++m)
#pragma unroll
        for (int n = 0; n < 4; ++n)
#pragma unroll
            for (int j = 0; j < 4; ++j) {
                int e = e0 + wid * 32 + m * 16 + lh * 4 + j;
                w[(size_t)e * 64 + n * 16 + lr] = acc[m][n][j] * s;
            }
}

// ---- edge products: scal (bf16) + fused V_out GEMM (K=192) ----
__launch_bounds__(256)
__global__ void edge_kernel(const int* __restrict__ senders, const float4* __restrict__ agg4,
                            const float4* __restrict__ V4, const u16* __restrict__ Wlt,
                            u16* __restrict__ scal, float* __restrict__ Vout) {
    __shared__ u16 a_lds[3][32][200];
    __shared__ u16 w_lds[64 * 200];
    const int t = threadIdx.x;
    const int e0 = blockIdx.x * 32;
#pragma unroll
    for (int i = 0; i < 6; ++i) {
        int c = i * 256 + t;
        int row = c / 24, off = (c % 24) * 8;
        *(uint4*)((char*)w_lds + row * 400 + off * 2) = ((const uint4*)Wlt)[c];
    }
    const float invs3 = 0.5773502691896258f;
    const float invs2 = 0.7071067811865476f;
    const float EPS = 0.24253562503633297f;
#pragma unroll
    for (int i = 0; i < 8; ++i) {
        int el = i * 4 + (t >> 6);
        int m = t & 63;
        int e = e0 + el;
        int s = senders[e];
        float4 a = agg4[(size_t)s * 64 + m];
        a.x *= EPS; a.y *= EPS; a.z *= EPS; a.w *= EPS;
        float4 b = V4[(size_t)e * 64 + m];
        float s0 = a.x * b.x;
        float s1 = (a.y * b.y + a.z * b.z + a.w * b.w) * invs3;
        scal[(size_t)e * 128 + m] = f2bf(s0);
        scal[(size_t)e * 128 + 64 + m] = f2bf(s1);
        float cx = (a.z * b.w - a.w * b.z) * invs2;
        float cy = (a.w * b.y - a.y * b.w) * invs2;
        float cz = (a.y * b.z - a.z * b.y) * invs2;
        a_lds[0][el][m] = f2bf(a.x * b.y);
        a_lds[0][el][64 + m] = f2bf(a.y * b.x);
        a_lds[0][el][128 + m] = f2bf(cx);
        a_lds[1][el][m] = f2bf(a.x * b.z);
        a_lds[1][el][64 + m] = f2bf(a.z * b.x);
        a_lds[1][el][128 + m] = f2bf(cy);
        a_lds[2][el][m] = f2bf(a.x * b.w);
        a_lds[2][el][64 + m] = f2bf(a.w * b.x);
        a_lds[2][el][128 + m] = f2bf(cz);
    }
    __syncthreads();
    const int lane = t & 63, wid = t >> 6;
    const int lr = lane & 15, lh = lane >> 4;
    f32x4 acc[3][2] = {};
    for (int kt = 0; kt < 6; ++kt) {
        bf16x8 bfr = *(const bf16x8*)((const char*)w_lds + (wid * 16 + lr) * 400 + kt * 64 + lh * 16);
#pragma unroll
        for (int c = 0; c < 3; ++c)
#pragma unroll
            for (int m = 0; m < 2; ++m) {
                bf16x8 afr = *(const bf16x8*)((const char*)a_lds + ((c * 32 + m * 16 + lr) * 400) + kt * 64 + lh * 16);
                acc[c][m] = __builtin_amdgcn_mfma_f32_16x16x32_bf16(afr, bfr, acc[c][m], 0, 0, 0);
            }
    }
    __syncthreads();
    float* ot = (float*)a_lds;
    const float sc = 0.07216878364870323f; // 1/sqrt(192)
#pragma unroll
    for (int c = 0; c < 3; ++c)
#pragma unroll
        for (int m = 0; m < 2; ++m)
#pragma unroll
            for (int j = 0; j < 4; ++j) {
                int row = m * 16 + lh * 4 + j;
                int mul = wid * 16 + lr;
                ot[row * 192 + mul * 3 + c] = acc[c][m][j] * sc;
            }
    __syncthreads();
    float4* vo = (float4*)(Vout + (size_t)e0 * 192);
#pragma unroll
    for (int i = 0; i < 6; ++i)
        vo[i * 256 + t] = ((float4*)ot)[i * 256 + t];
}

// ---- MLP GEMM 128x128xBK64, m97-style global_load_lds staging ----
// MODE 0: silu->bf16, MODE 1: env-scale->f32
template <int MODE>
__launch_bounds__(256)
__global__ void mlp_gemm(const u16* __restrict__ A, const u16* __restrict__ A2,
                         const u16* __restrict__ Bt, const int K, const float scale,
                         const float* __restrict__ env,
                         u16* __restrict__ outb, float* __restrict__ outf) {
    __shared__ u16 As[128 * 64];
    __shared__ u16 Bs[128 * 64];
    // bijective XCD swizzle: nwg % 8 == 0
    const int nwg = gridDim.x;
    const int bid = blockIdx.x;
    const int swz = (bid & 7) * (nwg >> 3) + (bid >> 3);
    const int mt = swz >> 2, nt = swz & 3;
    const int e0 = mt << 7, n0 = nt << 7;
    const int t = threadIdx.x, lane = t & 63, wid = t >> 6;
    const int wm = wid & 1, wn = wid >> 1;
    const int lr = lane & 15, lh = lane >> 4;
    f32x4 acc[4][4] = {};
    const int nkt = K >> 6;
    const int srow = wid * 8 + (lane >> 3); // staging row within 32-row group
    const int scol = (lane & 7) * 8;        // staging col (elements)
    for (int kt = 0; kt < nkt; ++kt) {
        const int kk = kt << 6;
        const int col = kk + scol;
#pragma unroll
        for (int i = 0; i < 4; ++i) {
            const int row = e0 + i * 32 + srow;
            const u16* g;
            if (A2 && col >= 512) g = A2 + (size_t)row * 128 + (col - 512);
            else                  g = A + (size_t)row * 512 + col;
            gload16(g, As + i * 2048 + wid * 512);
        }
#pragma unroll
        for (int i = 0; i < 4; ++i) {
            const int row = n0 + i * 32 + srow;
            const u16* g = Bt + (size_t)row * K + col;
            gload16(g, Bs + i * 2048 + wid * 512);
        }
        __syncthreads();
#pragma unroll
        for (int k2 = 0; k2 < 2; ++k2) {
            bf16x8 af[4], bfr[4];
#pragma unroll
            for (int m = 0; m < 4; ++m)
                af[m] = *(const bf16x8*)(As + (wm * 64 + m * 16 + lr) * 64 + k2 * 32 + lh * 8);
#pragma unroll
            for (int n = 0; n < 4; ++n)
                bfr[n] = *(const bf16x8*)(Bs + (wn * 64 + n * 16 + lr) * 64 + k2 * 32 + lh * 8);
#pragma unroll
            for (int m = 0; m < 4; ++m)
#pragma unroll
                for (int n = 0; n < 4; ++n)
                    acc[m][n] = __builtin_amdgcn_mfma_f32_16x16x32_bf16(af[m], bfr[n], acc[m][n], 0, 0, 0);
        }
        __syncthreads();
    }
#pragma unroll
    for (int m = 0; m < 4; ++m) {
#pragma unroll
        for (int j = 0; j < 4; ++j) {
            const int row = e0 + wm * 64 + m * 16 + lh * 4 + j;
            float ev = (MODE == 1) ? env[row] : 0.0f;
#pragma unroll
            for (int n = 0; n < 4; ++n) {
                const int col = n0 + wn * 64 + n * 16 + lr;
                float v = acc[m][n][j] * scale;
                if (MODE == 0) {
                    float sv = v / (1.0f + __expf(-v));
                    outb[(size_t)row * 512 + col] = f2bf(sv);
                } else {
                    outf[(size_t)row * 512 + col] = v * ev;
                }
            }
        }
    }
}

extern "C" void kernel_launch(void* const* d_in, const int* in_sizes, int n_in,
                              void* d_out, int out_size, void* d_ws, size_t ws_size,
                              hipStream_t stream) {
    const float* vectors = (const float*)d_in[0];
    const float* x       = (const float*)d_in[1];
    const float* V       = (const float*)d_in[2];
    const int*   senders = (const int*)d_in[3];
    const float* W_w     = (const float*)d_in[4];
    const float* W1      = (const float*)d_in[5];
    const float* W2      = (const float*)d_in[6];
    const float* W3      = (const float*)d_in[7];
    const float* W_lin   = (const float*)d_in[8];
    float* out = (float*)d_out;
    char* ws = (char*)d_ws;

    u16*    XB   = (u16*)(ws + 0x0);          // E*512 bf16
    u16*    H1   = (u16*)(ws + 0x8000000);    // E*512 bf16
    u16*    SCAL = (u16*)(ws + 0x10000000);   // E*128 bf16
    float*  AGG  = (float*)(ws + 0x12000000); // 8192*256 f32
    float*  ENV  = (float*)(ws + 0x12800000); // E f32
    float4* Yb   = (float4*)(ws + 0x12880000);// E float4
    float*  Wbuf = (float*)(ws + 0x12A80000); // E*64 f32
    u16*    WT   = (u16*)(ws + 0x14A80000);   // weights bf16
    u16* Wwt = WT;                 // 64 x 512
    u16* W1t = Wwt + 64 * 512;     // 512 x 640
    u16* W2t = W1t + 512 * 640;    // 512 x 512
    u16* W3t = W2t + 512 * 512;    // 512 x 512
    u16* Wlt = W3t + 512 * 512;    // 64 x 192
    u16* H2 = XB;                  // reuse XB for h2
    // sort scratch
    int* COUNT = (int*)(ws + 0x15000000);     // 8192
    int* OFF   = (int*)(ws + 0x15010000);     // 8193
    int* CURS  = (int*)(ws + 0x15020000);     // 8192
    int* PERM  = (int*)(ws + 0x15030000);     // E

    hipMemsetAsync(COUNT, 0, NNODES * sizeof(int), stream);

    wconv_kernel<<<(64 * 512) / 256, 256, 0, stream>>>(W_w, Wwt, 512, 64);
    wconv_kernel<<<(512 * 640) / 256, 256, 0, stream>>>(W1, W1t, 640, 512);
    wconv_kernel<<<(512 * 512) / 256, 256, 0, stream>>>(W2, W2t, 512, 512);
    wconv_kernel<<<(512 * 512) / 256, 256, 0, stream>>>(W3, W3t, 512, 512);
    wconv_kernel<<<(64 * 192) / 256, 256, 0, stream>>>(W_lin, Wlt, 192, 64);

    xconv_kernel<<<(E_TOT * 512 / 4) / 256, 256, 0, stream>>>((const float4*)x, (ushort4*)XB);
    envy_kernel<<<E_TOT / 256, 256, 0, stream>>>(vectors, ENV, Yb);

    hist_kernel<<<E_TOT / 256, 256, 0, stream>>>(senders, COUNT);
    scan_kernel<<<1, 1024, 0, stream>>>(COUNT, OFF, CURS);
    permbuild_kernel<<<E_TOT / 256, 256, 0, stream>>>(senders, CURS, PERM);

    wgemm_kernel<<<E_TOT / 128, 256, 0, stream>>>(XB, Wwt, Wbuf);
    gather_kernel<<<NNODES / 4, 256, 0, stream>>>(Wbuf, Yb, OFF, PERM, (float4*)AGG);

    edge_kernel<<<E_TOT / 32, 256, 0, stream>>>(senders, (const float4*)AGG, (const float4*)V,
                                                Wlt, SCAL, out + (size_t)E_TOT * 512);

    const float s640 = 0.03952847075210474f;  // 1/sqrt(640)
    const float s512 = 0.044194173824159216f; // 1/sqrt(512)
    mlp_gemm<0><<<(E_TOT / 128) * 4, 256, 0, stream>>>(XB, SCAL, W1t, 640, s640, nullptr, H1, nullptr);
    mlp_gemm<0><<<(E_TOT / 128) * 4, 256, 0, stream>>>(H1, nullptr, W2t, 512, s512, nullptr, H2, nullptr);
    mlp_gemm<1><<<(E_TOT / 128) * 4, 256, 0, stream>>>(H2, nullptr, W3t, 512, s512, ENV, nullptr, out);
}

// Round 3
// 650.762 us; speedup vs baseline: 1.7054x; 1.1181x over previous
//
#include <hip/hip_runtime.h>
#include <cstdint>
#include <cstddef>

#define E_TOT 131072
#define NNODES 8192

typedef __attribute__((ext_vector_type(8))) short bf16x8;
typedef __attribute__((ext_vector_type(4))) float f32x4;
typedef unsigned short u16;
typedef unsigned int u32;

__device__ __forceinline__ u16 f2bf(float f) {
    u32 u = __builtin_bit_cast(u32, f);
    u32 r = (u + 0x7FFFu + ((u >> 16) & 1u)) >> 16;
    return (u16)r;
}

__device__ __forceinline__ void gload16(const u16* g, u16* l) {
    __builtin_amdgcn_global_load_lds((const __attribute__((address_space(1))) void*)g,
                                     (__attribute__((address_space(3))) void*)l, 16, 0, 0);
}

// swizzled LDS fragment read: rows are 128 B; byte col XORed with (row&7)<<4
__device__ __forceinline__ bf16x8 lds_frag(const u16* base, int row, int bytecol) {
    return *(const bf16x8*)((const char*)base + row * 128 + (bytecol ^ ((row & 7) << 4)));
}

// ---- weight convert + transpose: dst[n*K+k] = bf16(src[k*N+n]) ----
__global__ void wconv_kernel(const float* __restrict__ src, u16* __restrict__ dst,
                             int K, int N) {
    int idx = blockIdx.x * 256 + threadIdx.x;
    if (idx >= N * K) return;
    int n = idx / K, k = idx - n * K;
    dst[idx] = f2bf(src[(size_t)k * N + n]);
}

// ---- x f32 -> bf16 ----
__global__ void xconv_kernel(const float4* __restrict__ x, ushort4* __restrict__ xb) {
    size_t i = (size_t)blockIdx.x * 256 + threadIdx.x;
    float4 v = x[i];
    ushort4 o;
    o.x = f2bf(v.x); o.y = f2bf(v.y); o.z = f2bf(v.z); o.w = f2bf(v.w);
    xb[i] = o;
}

// ---- envelope(r) and Y = [1, sqrt3*nhat] per edge ----
__global__ void envy_kernel(const float* __restrict__ vectors, float* __restrict__ env,
                            float4* __restrict__ Y) {
    int e = blockIdx.x * 256 + threadIdx.x;
    float vx = vectors[3 * e + 0], vy = vectors[3 * e + 1], vz = vectors[3 * e + 2];
    float r2 = vx * vx + vy * vy + vz * vz;
    float r = sqrtf(r2);
    float u6 = r2 * r2 * r2;
    float f = 1.0f + u6 * (-28.0f + 48.0f * r - 21.0f * r2);
    env[e] = (r < 1.0f) ? f : 0.0f;
    float inv = 1.7320508075688772f / r;
    Y[e] = make_float4(1.0f, vx * inv, vy * inv, vz * inv);
}

// ---- counting sort: histogram ----
__global__ void hist_kernel(const int* __restrict__ senders, int* __restrict__ cnt) {
    int e = blockIdx.x * 256 + threadIdx.x;
    atomicAdd(&cnt[senders[e]], 1);
}

// ---- single-block exclusive scan of 8192 counts -> off[8193], curs[8192] ----
__launch_bounds__(1024)
__global__ void scan_kernel(const int* __restrict__ cnt, int* __restrict__ off,
                            int* __restrict__ curs) {
    __shared__ int part[1024];
    const int t = threadIdx.x;
    int local[8];
    int s = 0;
#pragma unroll
    for (int j = 0; j < 8; ++j) { local[j] = cnt[t * 8 + j]; s += local[j]; }
    part[t] = s;
    __syncthreads();
    for (int d = 1; d < 1024; d <<= 1) {
        int v = (t >= d) ? part[t - d] : 0;
        __syncthreads();
        part[t] += v;
        __syncthreads();
    }
    int run = part[t] - s; // exclusive base
#pragma unroll
    for (int j = 0; j < 8; ++j) {
        off[t * 8 + j] = run;
        curs[t * 8 + j] = run;
        run += local[j];
    }
    if (t == 1023) off[8192] = run;
}

// ---- perm build: perm[pos] = e ----
__global__ void permbuild_kernel(const int* __restrict__ senders, int* __restrict__ curs,
                                 int* __restrict__ perm) {
    int e = blockIdx.x * 256 + threadIdx.x;
    int s = senders[e];
    int p = atomicAdd(&curs[s], 1);
    perm[p] = e;
}

// ---- gather segment-sum: agg[n][m][:] = sum_{e in seg(n)} w[e][m]*Y[e] ----
__launch_bounds__(256)
__global__ void gather_kernel(const float* __restrict__ w, const float4* __restrict__ Y,
                              const int* __restrict__ off, const int* __restrict__ perm,
                              float4* __restrict__ agg) {
    const int t = threadIdx.x;
    const int n = blockIdx.x * 4 + (t >> 6);
    const int m = t & 63;
    const int beg = off[n], end = off[n + 1];
    float4 acc = make_float4(0.f, 0.f, 0.f, 0.f);
    for (int i = beg; i < end; ++i) {
        int e = perm[i];
        float wv = w[(size_t)e * 64 + m];
        float4 y = Y[e];
        acc.x += wv * y.x; acc.y += wv * y.y; acc.z += wv * y.z; acc.w += wv * y.w;
    }
    agg[(size_t)n * 64 + m] = acc;
}

// ---- w = x @ W_w / sqrt(512): M=E, N=64, K=512, tile 128x64xBK64 ----
__launch_bounds__(256)
__global__ void wgemm_kernel(const u16* __restrict__ XB, const u16* __restrict__ Wt,
                             float* __restrict__ w) {
    __shared__ u16 As[128 * 72];
    __shared__ u16 Bs[64 * 72];
    const int e0 = blockIdx.x * 128;
    const int t = threadIdx.x, lane = t & 63, wid = t >> 6;
    const int lr = lane & 15, lh = lane >> 4;
    const int r8 = t >> 3, c8 = t & 7;
    f32x4 acc[2][4] = {};
    for (int kt = 0; kt < 8; ++kt) {
        const int kk = kt << 6;
#pragma unroll
        for (int i = 0; i < 4; ++i) {
            int row = i * 32 + r8;
            const u16* g = XB + (size_t)(e0 + row) * 512 + kk + c8 * 8;
            *(uint4*)((char*)As + row * 144 + c8 * 16) = *(const uint4*)g;
        }
#pragma unroll
        for (int i = 0; i < 2; ++i) {
            int row = i * 32 + r8;
            const u16* g = Wt + (size_t)row * 512 + kk + c8 * 8;
            *(uint4*)((char*)Bs + row * 144 + c8 * 16) = *(const uint4*)g;
        }
        __syncthreads();
#pragma unroll
        for (int k2 = 0; k2 < 2; ++k2) {
            bf16x8 af[2], bfr[4];
#pragma unroll
            for (int m = 0; m < 2; ++m)
                af[m] = *(const bf16x8*)((const char*)As + (wid * 32 + m * 16 + lr) * 144 + k2 * 64 + lh * 16);
#pragma unroll
            for (int n = 0; n < 4; ++n)
                bfr[n] = *(const bf16x8*)((const char*)Bs + (n * 16 + lr) * 144 + k2 * 64 + lh * 16);
#pragma unroll
            for (int m = 0; m < 2; ++m)
#pragma unroll
                for (int n = 0; n < 4; ++n)
                    acc[m][n] = __builtin_amdgcn_mfma_f32_16x16x32_bf16(af[m], bfr[n], acc[m][n], 0, 0, 0);
        }
        __syncthreads();
    }
    const float s = 0.044194173824159216f; // 1/sqrt(512)
#pragma unroll
    for (int m = 0; m < 2; ++m)
#pragma unroll
        for (int n = 0; n < 4; ++n)
#pragma unroll
            for (int j = 0; j < 4; ++j) {
                int e = e0 + wid * 32 + m * 16 + lh * 4 + j;
                w[(size_t)e * 64 + n * 16 + lr] = acc[m][n][j] * s;
            }
}

// ---- edge products: scal (bf16) + fused V_out GEMM (K=192) ----
__launch_bounds__(256)
__global__ void edge_kernel(const int* __restrict__ senders, const float4* __restrict__ agg4,
                            const float4* __restrict__ V4, const u16* __restrict__ Wlt,
                            u16* __restrict__ scal, float* __restrict__ Vout) {
    __shared__ u16 a_lds[3][32][200];
    __shared__ u16 w_lds[64 * 200];
    const int t = threadIdx.x;
    const int e0 = blockIdx.x * 32;
#pragma unroll
    for (int i = 0; i < 6; ++i) {
        int c = i * 256 + t;
        int row = c / 24, off = (c % 24) * 8;
        *(uint4*)((char*)w_lds + row * 400 + off * 2) = ((const uint4*)Wlt)[c];
    }
    const float invs3 = 0.5773502691896258f;
    const float invs2 = 0.7071067811865476f;
    const float EPS = 0.24253562503633297f;
#pragma unroll
    for (int i = 0; i < 8; ++i) {
        int el = i * 4 + (t >> 6);
        int m = t & 63;
        int e = e0 + el;
        int s = senders[e];
        float4 a = agg4[(size_t)s * 64 + m];
        a.x *= EPS; a.y *= EPS; a.z *= EPS; a.w *= EPS;
        float4 b = V4[(size_t)e * 64 + m];
        float s0 = a.x * b.x;
        float s1 = (a.y * b.y + a.z * b.z + a.w * b.w) * invs3;
        scal[(size_t)e * 128 + m] = f2bf(s0);
        scal[(size_t)e * 128 + 64 + m] = f2bf(s1);
        float cx = (a.z * b.w - a.w * b.z) * invs2;
        float cy = (a.w * b.y - a.y * b.w) * invs2;
        float cz = (a.y * b.z - a.z * b.y) * invs2;
        a_lds[0][el][m] = f2bf(a.x * b.y);
        a_lds[0][el][64 + m] = f2bf(a.y * b.x);
        a_lds[0][el][128 + m] = f2bf(cx);
        a_lds[1][el][m] = f2bf(a.x * b.z);
        a_lds[1][el][64 + m] = f2bf(a.z * b.x);
        a_lds[1][el][128 + m] = f2bf(cy);
        a_lds[2][el][m] = f2bf(a.x * b.w);
        a_lds[2][el][64 + m] = f2bf(a.w * b.x);
        a_lds[2][el][128 + m] = f2bf(cz);
    }
    __syncthreads();
    const int lane = t & 63, wid = t >> 6;
    const int lr = lane & 15, lh = lane >> 4;
    f32x4 acc[3][2] = {};
    for (int kt = 0; kt < 6; ++kt) {
        bf16x8 bfr = *(const bf16x8*)((const char*)w_lds + (wid * 16 + lr) * 400 + kt * 64 + lh * 16);
#pragma unroll
        for (int c = 0; c < 3; ++c)
#pragma unroll
            for (int m = 0; m < 2; ++m) {
                bf16x8 afr = *(const bf16x8*)((const char*)a_lds + ((c * 32 + m * 16 + lr) * 400) + kt * 64 + lh * 16);
                acc[c][m] = __builtin_amdgcn_mfma_f32_16x16x32_bf16(afr, bfr, acc[c][m], 0, 0, 0);
            }
    }
    __syncthreads();
    float* ot = (float*)a_lds;
    const float sc = 0.07216878364870323f; // 1/sqrt(192)
#pragma unroll
    for (int c = 0; c < 3; ++c)
#pragma unroll
        for (int m = 0; m < 2; ++m)
#pragma unroll
            for (int j = 0; j < 4; ++j) {
                int row = m * 16 + lh * 4 + j;
                int mul = wid * 16 + lr;
                ot[row * 192 + mul * 3 + c] = acc[c][m][j] * sc;
            }
    __syncthreads();
    float4* vo = (float4*)(Vout + (size_t)e0 * 192);
#pragma unroll
    for (int i = 0; i < 6; ++i)
        vo[i * 256 + t] = ((float4*)ot)[i * 256 + t];
}

// ---- MLP GEMM 128x128xBK64, global_load_lds + st-swizzle (rule #21) ----
// LDS dest linear; global source col pre-permuted; reads XOR (row&7)<<4.
// MODE 0: silu->bf16, MODE 1: env-scale->f32
template <int MODE>
__launch_bounds__(256)
__global__ void mlp_gemm(const u16* __restrict__ A, const u16* __restrict__ A2,
                         const u16* __restrict__ Bt, const int K, const float scale,
                         const float* __restrict__ env,
                         u16* __restrict__ outb, float* __restrict__ outf) {
    __shared__ u16 As[128 * 64];
    __shared__ u16 Bs[128 * 64];
    // bijective XCD swizzle: nwg % 8 == 0
    const int nwg = gridDim.x;
    const int bid = blockIdx.x;
    const int swz = (bid & 7) * (nwg >> 3) + (bid >> 3);
    const int mt = swz >> 2, nt = swz & 3;
    const int e0 = mt << 7, n0 = nt << 7;
    const int t = threadIdx.x, lane = t & 63, wid = t >> 6;
    const int wm = wid & 1, wn = wid >> 1;
    const int lr = lane & 15, lh = lane >> 4;
    f32x4 acc[4][4] = {};
    const int nkt = K >> 6;
    const int srow = wid * 8 + (lane >> 3);            // staging row within 32-row group
    const int scol = ((lane & 7) ^ (lane >> 3)) * 8;   // SWIZZLED source col (elements)
    for (int kt = 0; kt < nkt; ++kt) {
        const int kk = kt << 6;
        const int col = kk + scol;
#pragma unroll
        for (int i = 0; i < 4; ++i) {
            const int row = e0 + i * 32 + srow;
            const u16* g;
            if (A2 && kk >= 512) g = A2 + (size_t)row * 128 + (col - 512);
            else                 g = A + (size_t)row * 512 + col;
            gload16(g, As + i * 2048 + wid * 512);
        }
#pragma unroll
        for (int i = 0; i < 4; ++i) {
            const int row = n0 + i * 32 + srow;
            const u16* g = Bt + (size_t)row * K + col;
            gload16(g, Bs + i * 2048 + wid * 512);
        }
        __syncthreads();
#pragma unroll
        for (int k2 = 0; k2 < 2; ++k2) {
            bf16x8 af[4], bfr[4];
#pragma unroll
            for (int m = 0; m < 4; ++m)
                af[m] = lds_frag(As, wm * 64 + m * 16 + lr, k2 * 64 + lh * 16);
#pragma unroll
            for (int n = 0; n < 4; ++n)
                bfr[n] = lds_frag(Bs, wn * 64 + n * 16 + lr, k2 * 64 + lh * 16);
#pragma unroll
            for (int m = 0; m < 4; ++m)
#pragma unroll
                for (int n = 0; n < 4; ++n)
                    acc[m][n] = __builtin_amdgcn_mfma_f32_16x16x32_bf16(af[m], bfr[n], acc[m][n], 0, 0, 0);
        }
        __syncthreads();
    }
#pragma unroll
    for (int m = 0; m < 4; ++m) {
#pragma unroll
        for (int j = 0; j < 4; ++j) {
            const int row = e0 + wm * 64 + m * 16 + lh * 4 + j;
            float ev = (MODE == 1) ? env[row] : 0.0f;
#pragma unroll
            for (int n = 0; n < 4; ++n) {
                const int col = n0 + wn * 64 + n * 16 + lr;
                float v = acc[m][n][j] * scale;
                if (MODE == 0) {
                    float sv = v / (1.0f + __expf(-v));
                    outb[(size_t)row * 512 + col] = f2bf(sv);
                } else {
                    outf[(size_t)row * 512 + col] = v * ev;
                }
            }
        }
    }
}

extern "C" void kernel_launch(void* const* d_in, const int* in_sizes, int n_in,
                              void* d_out, int out_size, void* d_ws, size_t ws_size,
                              hipStream_t stream) {
    const float* vectors = (const float*)d_in[0];
    const float* x       = (const float*)d_in[1];
    const float* V       = (const float*)d_in[2];
    const int*   senders = (const int*)d_in[3];
    const float* W_w     = (const float*)d_in[4];
    const float* W1      = (const float*)d_in[5];
    const float* W2      = (const float*)d_in[6];
    const float* W3      = (const float*)d_in[7];
    const float* W_lin   = (const float*)d_in[8];
    float* out = (float*)d_out;
    char* ws = (char*)d_ws;

    u16*    XB   = (u16*)(ws + 0x0);          // E*512 bf16
    u16*    H1   = (u16*)(ws + 0x8000000);    // E*512 bf16
    u16*    SCAL = (u16*)(ws + 0x10000000);   // E*128 bf16
    float*  AGG  = (float*)(ws + 0x12000000); // 8192*256 f32
    float*  ENV  = (float*)(ws + 0x12800000); // E f32
    float4* Yb   = (float4*)(ws + 0x12880000);// E float4
    float*  Wbuf = (float*)(ws + 0x12A80000); // E*64 f32
    u16*    WT   = (u16*)(ws + 0x14A80000);   // weights bf16
    u16* Wwt = WT;                 // 64 x 512
    u16* W1t = Wwt + 64 * 512;     // 512 x 640
    u16* W2t = W1t + 512 * 640;    // 512 x 512
    u16* W3t = W2t + 512 * 512;    // 512 x 512
    u16* Wlt = W3t + 512 * 512;    // 64 x 192
    u16* H2 = XB;                  // reuse XB for h2
    // sort scratch
    int* COUNT = (int*)(ws + 0x15000000);     // 8192
    int* OFF   = (int*)(ws + 0x15010000);     // 8193
    int* CURS  = (int*)(ws + 0x15020000);     // 8192
    int* PERM  = (int*)(ws + 0x15030000);     // E

    hipMemsetAsync(COUNT, 0, NNODES * sizeof(int), stream);

    wconv_kernel<<<(64 * 512) / 256, 256, 0, stream>>>(W_w, Wwt, 512, 64);
    wconv_kernel<<<(512 * 640) / 256, 256, 0, stream>>>(W1, W1t, 640, 512);
    wconv_kernel<<<(512 * 512) / 256, 256, 0, stream>>>(W2, W2t, 512, 512);
    wconv_kernel<<<(512 * 512) / 256, 256, 0, stream>>>(W3, W3t, 512, 512);
    wconv_kernel<<<(64 * 192) / 256, 256, 0, stream>>>(W_lin, Wlt, 192, 64);

    xconv_kernel<<<(E_TOT * 512 / 4) / 256, 256, 0, stream>>>((const float4*)x, (ushort4*)XB);
    envy_kernel<<<E_TOT / 256, 256, 0, stream>>>(vectors, ENV, Yb);

    hist_kernel<<<E_TOT / 256, 256, 0, stream>>>(senders, COUNT);
    scan_kernel<<<1, 1024, 0, stream>>>(COUNT, OFF, CURS);
    permbuild_kernel<<<E_TOT / 256, 256, 0, stream>>>(senders, CURS, PERM);

    wgemm_kernel<<<E_TOT / 128, 256, 0, stream>>>(XB, Wwt, Wbuf);
    gather_kernel<<<NNODES / 4, 256, 0, stream>>>(Wbuf, Yb, OFF, PERM, (float4*)AGG);

    edge_kernel<<<E_TOT / 32, 256, 0, stream>>>(senders, (const float4*)AGG, (const float4*)V,
                                                Wlt, SCAL, out + (size_t)E_TOT * 512);

    const float s640 = 0.03952847075210474f;  // 1/sqrt(640)
    const float s512 = 0.044194173824159216f; // 1/sqrt(512)
    mlp_gemm<0><<<(E_TOT / 128) * 4, 256, 0, stream>>>(XB, SCAL, W1t, 640, s640, nullptr, H1, nullptr);
    mlp_gemm<0><<<(E_TOT / 128) * 4, 256, 0, stream>>>(H1, nullptr, W2t, 512, s512, nullptr, H2, nullptr);
    mlp_gemm<1><<<(E_TOT / 128) * 4, 256, 0, stream>>>(H2, nullptr, W3t, 512, s512, ENV, nullptr, out);
}

// Round 4
// 600.904 us; speedup vs baseline: 1.8469x; 1.0830x over previous
//
#include <hip/hip_runtime.h>
#include <cstdint>
#include <cstddef>

#define E_TOT 131072
#define NNODES 8192

typedef __attribute__((ext_vector_type(8))) short bf16x8;
typedef __attribute__((ext_vector_type(4))) float f32x4;
typedef unsigned short u16;
typedef unsigned int u32;

__device__ __forceinline__ u16 f2bf(float f) {
    u32 u = __builtin_bit_cast(u32, f);
    u32 r = (u + 0x7FFFu + ((u >> 16) & 1u)) >> 16;
    return (u16)r;
}

__device__ __forceinline__ void gload16(const u16* g, u16* l) {
    __builtin_amdgcn_global_load_lds((const __attribute__((address_space(1))) void*)g,
                                     (__attribute__((address_space(3))) void*)l, 16, 0, 0);
}

// swizzled LDS fragment read: rows are 128 B; byte col XORed with (row&7)<<4
__device__ __forceinline__ bf16x8 lds_frag(const u16* base, int row, int bytecol) {
    return *(const bf16x8*)((const char*)base + row * 128 + (bytecol ^ ((row & 7) << 4)));
}

// ---- weight convert + transpose: dst[n*K+k] = bf16(src[k*N+n]) ----
__global__ void wconv_kernel(const float* __restrict__ src, u16* __restrict__ dst,
                             int K, int N) {
    int idx = blockIdx.x * 256 + threadIdx.x;
    if (idx >= N * K) return;
    int n = idx / K, k = idx - n * K;
    dst[idx] = f2bf(src[(size_t)k * N + n]);
}

// ---- x f32 -> bf16 ----
__global__ void xconv_kernel(const float4* __restrict__ x, ushort4* __restrict__ xb) {
    size_t i = (size_t)blockIdx.x * 256 + threadIdx.x;
    float4 v = x[i];
    ushort4 o;
    o.x = f2bf(v.x); o.y = f2bf(v.y); o.z = f2bf(v.z); o.w = f2bf(v.w);
    xb[i] = o;
}

// ---- envelope(r) and Y = [1, sqrt3*nhat] per edge ----
__global__ void envy_kernel(const float* __restrict__ vectors, float* __restrict__ env,
                            float4* __restrict__ Y) {
    int e = blockIdx.x * 256 + threadIdx.x;
    float vx = vectors[3 * e + 0], vy = vectors[3 * e + 1], vz = vectors[3 * e + 2];
    float r2 = vx * vx + vy * vy + vz * vz;
    float r = sqrtf(r2);
    float u6 = r2 * r2 * r2;
    float f = 1.0f + u6 * (-28.0f + 48.0f * r - 21.0f * r2);
    env[e] = (r < 1.0f) ? f : 0.0f;
    float inv = 1.7320508075688772f / r;
    Y[e] = make_float4(1.0f, vx * inv, vy * inv, vz * inv);
}

// ---- counting sort: histogram ----
__global__ void hist_kernel(const int* __restrict__ senders, int* __restrict__ cnt) {
    int e = blockIdx.x * 256 + threadIdx.x;
    atomicAdd(&cnt[senders[e]], 1);
}

// ---- single-block exclusive scan of 8192 counts -> off[8193], curs[8192] ----
__launch_bounds__(1024)
__global__ void scan_kernel(const int* __restrict__ cnt, int* __restrict__ off,
                            int* __restrict__ curs) {
    __shared__ int part[1024];
    const int t = threadIdx.x;
    int local[8];
    int s = 0;
#pragma unroll
    for (int j = 0; j < 8; ++j) { local[j] = cnt[t * 8 + j]; s += local[j]; }
    part[t] = s;
    __syncthreads();
    for (int d = 1; d < 1024; d <<= 1) {
        int v = (t >= d) ? part[t - d] : 0;
        __syncthreads();
        part[t] += v;
        __syncthreads();
    }
    int run = part[t] - s; // exclusive base
#pragma unroll
    for (int j = 0; j < 8; ++j) {
        off[t * 8 + j] = run;
        curs[t * 8 + j] = run;
        run += local[j];
    }
    if (t == 1023) off[8192] = run;
}

// ---- perm build: perm[pos] = e ----
__global__ void permbuild_kernel(const int* __restrict__ senders, int* __restrict__ curs,
                                 int* __restrict__ perm) {
    int e = blockIdx.x * 256 + threadIdx.x;
    int s = senders[e];
    int p = atomicAdd(&curs[s], 1);
    perm[p] = e;
}

// ---- gather segment-sum: agg[n][m][:] = sum_{e in seg(n)} w[e][m]*Y[e] ----
__launch_bounds__(256)
__global__ void gather_kernel(const float* __restrict__ w, const float4* __restrict__ Y,
                              const int* __restrict__ off, const int* __restrict__ perm,
                              float4* __restrict__ agg) {
    const int t = threadIdx.x;
    const int n = blockIdx.x * 4 + (t >> 6);
    const int m = t & 63;
    const int beg = off[n], end = off[n + 1];
    float4 acc = make_float4(0.f, 0.f, 0.f, 0.f);
    for (int i = beg; i < end; ++i) {
        int e = perm[i];
        float wv = w[(size_t)e * 64 + m];
        float4 y = Y[e];
        acc.x += wv * y.x; acc.y += wv * y.y; acc.z += wv * y.z; acc.w += wv * y.w;
    }
    agg[(size_t)n * 64 + m] = acc;
}

// ---- w = x @ W_w / sqrt(512): M=E, N=64, K=512, tile 128x64xBK64 ----
__launch_bounds__(256)
__global__ void wgemm_kernel(const u16* __restrict__ XB, const u16* __restrict__ Wt,
                             float* __restrict__ w) {
    __shared__ u16 As[128 * 72];
    __shared__ u16 Bs[64 * 72];
    const int e0 = blockIdx.x * 128;
    const int t = threadIdx.x, lane = t & 63, wid = t >> 6;
    const int lr = lane & 15, lh = lane >> 4;
    const int r8 = t >> 3, c8 = t & 7;
    f32x4 acc[2][4] = {};
    for (int kt = 0; kt < 8; ++kt) {
        const int kk = kt << 6;
#pragma unroll
        for (int i = 0; i < 4; ++i) {
            int row = i * 32 + r8;
            const u16* g = XB + (size_t)(e0 + row) * 512 + kk + c8 * 8;
            *(uint4*)((char*)As + row * 144 + c8 * 16) = *(const uint4*)g;
        }
#pragma unroll
        for (int i = 0; i < 2; ++i) {
            int row = i * 32 + r8;
            const u16* g = Wt + (size_t)row * 512 + kk + c8 * 8;
            *(uint4*)((char*)Bs + row * 144 + c8 * 16) = *(const uint4*)g;
        }
        __syncthreads();
#pragma unroll
        for (int k2 = 0; k2 < 2; ++k2) {
            bf16x8 af[2], bfr[4];
#pragma unroll
            for (int m = 0; m < 2; ++m)
                af[m] = *(const bf16x8*)((const char*)As + (wid * 32 + m * 16 + lr) * 144 + k2 * 64 + lh * 16);
#pragma unroll
            for (int n = 0; n < 4; ++n)
                bfr[n] = *(const bf16x8*)((const char*)Bs + (n * 16 + lr) * 144 + k2 * 64 + lh * 16);
#pragma unroll
            for (int m = 0; m < 2; ++m)
#pragma unroll
                for (int n = 0; n < 4; ++n)
                    acc[m][n] = __builtin_amdgcn_mfma_f32_16x16x32_bf16(af[m], bfr[n], acc[m][n], 0, 0, 0);
        }
        __syncthreads();
    }
    const float s = 0.044194173824159216f; // 1/sqrt(512)
#pragma unroll
    for (int m = 0; m < 2; ++m)
#pragma unroll
        for (int n = 0; n < 4; ++n)
#pragma unroll
            for (int j = 0; j < 4; ++j) {
                int e = e0 + wid * 32 + m * 16 + lh * 4 + j;
                w[(size_t)e * 64 + n * 16 + lr] = acc[m][n][j] * s;
            }
}

// ---- edge products: scal (bf16) + fused V_out GEMM (K=192) ----
__launch_bounds__(256)
__global__ void edge_kernel(const int* __restrict__ senders, const float4* __restrict__ agg4,
                            const float4* __restrict__ V4, const u16* __restrict__ Wlt,
                            u16* __restrict__ scal, float* __restrict__ Vout) {
    __shared__ u16 a_lds[3][32][200];
    __shared__ u16 w_lds[64 * 200];
    const int t = threadIdx.x;
    const int e0 = blockIdx.x * 32;
#pragma unroll
    for (int i = 0; i < 6; ++i) {
        int c = i * 256 + t;
        int row = c / 24, off = (c % 24) * 8;
        *(uint4*)((char*)w_lds + row * 400 + off * 2) = ((const uint4*)Wlt)[c];
    }
    const float invs3 = 0.5773502691896258f;
    const float invs2 = 0.7071067811865476f;
    const float EPS = 0.24253562503633297f;
#pragma unroll
    for (int i = 0; i < 8; ++i) {
        int el = i * 4 + (t >> 6);
        int m = t & 63;
        int e = e0 + el;
        int s = senders[e];
        float4 a = agg4[(size_t)s * 64 + m];
        a.x *= EPS; a.y *= EPS; a.z *= EPS; a.w *= EPS;
        float4 b = V4[(size_t)e * 64 + m];
        float s0 = a.x * b.x;
        float s1 = (a.y * b.y + a.z * b.z + a.w * b.w) * invs3;
        scal[(size_t)e * 128 + m] = f2bf(s0);
        scal[(size_t)e * 128 + 64 + m] = f2bf(s1);
        float cx = (a.z * b.w - a.w * b.z) * invs2;
        float cy = (a.w * b.y - a.y * b.w) * invs2;
        float cz = (a.y * b.z - a.z * b.y) * invs2;
        a_lds[0][el][m] = f2bf(a.x * b.y);
        a_lds[0][el][64 + m] = f2bf(a.y * b.x);
        a_lds[0][el][128 + m] = f2bf(cx);
        a_lds[1][el][m] = f2bf(a.x * b.z);
        a_lds[1][el][64 + m] = f2bf(a.z * b.x);
        a_lds[1][el][128 + m] = f2bf(cy);
        a_lds[2][el][m] = f2bf(a.x * b.w);
        a_lds[2][el][64 + m] = f2bf(a.w * b.x);
        a_lds[2][el][128 + m] = f2bf(cz);
    }
    __syncthreads();
    const int lane = t & 63, wid = t >> 6;
    const int lr = lane & 15, lh = lane >> 4;
    f32x4 acc[3][2] = {};
    for (int kt = 0; kt < 6; ++kt) {
        bf16x8 bfr = *(const bf16x8*)((const char*)w_lds + (wid * 16 + lr) * 400 + kt * 64 + lh * 16);
#pragma unroll
        for (int c = 0; c < 3; ++c)
#pragma unroll
            for (int m = 0; m < 2; ++m) {
                bf16x8 afr = *(const bf16x8*)((const char*)a_lds + ((c * 32 + m * 16 + lr) * 400) + kt * 64 + lh * 16);
                acc[c][m] = __builtin_amdgcn_mfma_f32_16x16x32_bf16(afr, bfr, acc[c][m], 0, 0, 0);
            }
    }
    __syncthreads();
    float* ot = (float*)a_lds;
    const float sc = 0.07216878364870323f; // 1/sqrt(192)
#pragma unroll
    for (int c = 0; c < 3; ++c)
#pragma unroll
        for (int m = 0; m < 2; ++m)
#pragma unroll
            for (int j = 0; j < 4; ++j) {
                int row = m * 16 + lh * 4 + j;
                int mul = wid * 16 + lr;
                ot[row * 192 + mul * 3 + c] = acc[c][m][j] * sc;
            }
    __syncthreads();
    float4* vo = (float4*)(Vout + (size_t)e0 * 192);
#pragma unroll
    for (int i = 0; i < 6; ++i)
        vo[i * 256 + t] = ((float4*)ot)[i * 256 + t];
}

// ---- MLP GEMM: 256x256 tile, BK=64, 8 waves (2x4) of 128x64 output,
//      double-buffered LDS (128 KiB), stage-before-compute, 1 barrier/K-tile.
//      global_load_lds + both-sides XOR swizzle (rule #21).
//      MODE 0: silu->bf16, MODE 1: env-scale->f32
template <int MODE>
__launch_bounds__(512, 2)
__global__ void mlp_gemm(const u16* __restrict__ A, const u16* __restrict__ A2,
                         const u16* __restrict__ Bt, const int K, const float scale,
                         const float* __restrict__ env,
                         u16* __restrict__ outb, float* __restrict__ outf) {
    __shared__ u16 lds[2][2][256 * 64]; // [dbuf][A/B][row*64+col]
    const int nwg = gridDim.x;
    const int bid = blockIdx.x;
    const int swz = (bid & 7) * (nwg >> 3) + (bid >> 3); // bijective XCD swizzle
    const int mt = swz >> 1, nt = swz & 1;
    const int e0 = mt << 8, n0 = nt << 8;
    const int t = threadIdx.x, lane = t & 63, wid = t >> 6;
    const int wm = wid >> 2, wn = wid & 3;  // 2 x 4 wave grid
    const int lr = lane & 15, lh = lane >> 4;
    const int sr8 = lane >> 3;                    // 0..7
    const int scol = ((lane & 7) ^ sr8) << 3;     // pre-swizzled source col (elems)
    f32x4 acc[8][4] = {};
    const int nkt = K >> 6;

    for (int kt = 0; kt < nkt; ++kt) {
        // ---- stage NEXT (or first) tile before computing current ----
        if (kt == 0) {
            // prologue: stage tile 0 into buf 0, then barrier
            const int col = scol;
#pragma unroll
            for (int i = 0; i < 4; ++i) {
                const int row = e0 + i * 64 + wid * 8 + sr8;
                gload16(A + (size_t)row * 512 + col, &lds[0][0][i * 4096 + wid * 512]);
            }
#pragma unroll
            for (int i = 0; i < 4; ++i) {
                const int row = n0 + i * 64 + wid * 8 + sr8;
                gload16(Bt + (size_t)row * K + col, &lds[0][1][i * 4096 + wid * 512]);
            }
            __syncthreads();
        }
        if (kt + 1 < nkt) {
            const int kk = (kt + 1) << 6;
            const int col = kk + scol;
            const int nb = (kt + 1) & 1;
#pragma unroll
            for (int i = 0; i < 4; ++i) {
                const int row = e0 + i * 64 + wid * 8 + sr8;
                const u16* g;
                if (A2 && kk >= 512) g = A2 + (size_t)row * 128 + (col - 512);
                else                 g = A + (size_t)row * 512 + col;
                gload16(g, &lds[nb][0][i * 4096 + wid * 512]);
            }
#pragma unroll
            for (int i = 0; i < 4; ++i) {
                const int row = n0 + i * 64 + wid * 8 + sr8;
                gload16(Bt + (size_t)row * K + col, &lds[nb][1][i * 4096 + wid * 512]);
            }
        }
        // ---- compute current tile ----
        const u16* Ab = lds[kt & 1][0];
        const u16* Bb = lds[kt & 1][1];
#pragma unroll
        for (int k2 = 0; k2 < 2; ++k2) {
            bf16x8 af[8], bfr[4];
#pragma unroll
            for (int m = 0; m < 8; ++m)
                af[m] = lds_frag(Ab, wm * 128 + m * 16 + lr, k2 * 64 + lh * 16);
#pragma unroll
            for (int n = 0; n < 4; ++n)
                bfr[n] = lds_frag(Bb, wn * 64 + n * 16 + lr, k2 * 64 + lh * 16);
#pragma unroll
            for (int m = 0; m < 8; ++m)
#pragma unroll
                for (int n = 0; n < 4; ++n)
                    acc[m][n] = __builtin_amdgcn_mfma_f32_16x16x32_bf16(af[m], bfr[n], acc[m][n], 0, 0, 0);
        }
        // barrier: drains our prefetch (vmcnt) + protects WAR on the buffer
        __syncthreads();
    }
#pragma unroll
    for (int m = 0; m < 8; ++m) {
#pragma unroll
        for (int j = 0; j < 4; ++j) {
            const int row = e0 + wm * 128 + m * 16 + lh * 4 + j;
            float ev = (MODE == 1) ? env[row] : 0.0f;
#pragma unroll
            for (int n = 0; n < 4; ++n) {
                const int col = n0 + wn * 64 + n * 16 + lr;
                float v = acc[m][n][j] * scale;
                if (MODE == 0) {
                    float sv = v / (1.0f + __expf(-v));
                    outb[(size_t)row * 512 + col] = f2bf(sv);
                } else {
                    outf[(size_t)row * 512 + col] = v * ev;
                }
            }
        }
    }
}

extern "C" void kernel_launch(void* const* d_in, const int* in_sizes, int n_in,
                              void* d_out, int out_size, void* d_ws, size_t ws_size,
                              hipStream_t stream) {
    const float* vectors = (const float*)d_in[0];
    const float* x       = (const float*)d_in[1];
    const float* V       = (const float*)d_in[2];
    const int*   senders = (const int*)d_in[3];
    const float* W_w     = (const float*)d_in[4];
    const float* W1      = (const float*)d_in[5];
    const float* W2      = (const float*)d_in[6];
    const float* W3      = (const float*)d_in[7];
    const float* W_lin   = (const float*)d_in[8];
    float* out = (float*)d_out;
    char* ws = (char*)d_ws;

    u16*    XB   = (u16*)(ws + 0x0);          // E*512 bf16
    u16*    H1   = (u16*)(ws + 0x8000000);    // E*512 bf16
    u16*    SCAL = (u16*)(ws + 0x10000000);   // E*128 bf16
    float*  AGG  = (float*)(ws + 0x12000000); // 8192*256 f32
    float*  ENV  = (float*)(ws + 0x12800000); // E f32
    float4* Yb   = (float4*)(ws + 0x12880000);// E float4
    float*  Wbuf = (float*)(ws + 0x12A80000); // E*64 f32
    u16*    WT   = (u16*)(ws + 0x14A80000);   // weights bf16
    u16* Wwt = WT;                 // 64 x 512
    u16* W1t = Wwt + 64 * 512;     // 512 x 640
    u16* W2t = W1t + 512 * 640;    // 512 x 512
    u16* W3t = W2t + 512 * 512;    // 512 x 512
    u16* Wlt = W3t + 512 * 512;    // 64 x 192
    u16* H2 = XB;                  // reuse XB for h2
    // sort scratch
    int* COUNT = (int*)(ws + 0x15000000);     // 8192
    int* OFF   = (int*)(ws + 0x15010000);     // 8193
    int* CURS  = (int*)(ws + 0x15020000);     // 8192
    int* PERM  = (int*)(ws + 0x15030000);     // E

    hipMemsetAsync(COUNT, 0, NNODES * sizeof(int), stream);

    wconv_kernel<<<(64 * 512) / 256, 256, 0, stream>>>(W_w, Wwt, 512, 64);
    wconv_kernel<<<(512 * 640) / 256, 256, 0, stream>>>(W1, W1t, 640, 512);
    wconv_kernel<<<(512 * 512) / 256, 256, 0, stream>>>(W2, W2t, 512, 512);
    wconv_kernel<<<(512 * 512) / 256, 256, 0, stream>>>(W3, W3t, 512, 512);
    wconv_kernel<<<(64 * 192) / 256, 256, 0, stream>>>(W_lin, Wlt, 192, 64);

    xconv_kernel<<<(E_TOT * 512 / 4) / 256, 256, 0, stream>>>((const float4*)x, (ushort4*)XB);
    envy_kernel<<<E_TOT / 256, 256, 0, stream>>>(vectors, ENV, Yb);

    hist_kernel<<<E_TOT / 256, 256, 0, stream>>>(senders, COUNT);
    scan_kernel<<<1, 1024, 0, stream>>>(COUNT, OFF, CURS);
    permbuild_kernel<<<E_TOT / 256, 256, 0, stream>>>(senders, CURS, PERM);

    wgemm_kernel<<<E_TOT / 128, 256, 0, stream>>>(XB, Wwt, Wbuf);
    gather_kernel<<<NNODES / 4, 256, 0, stream>>>(Wbuf, Yb, OFF, PERM, (float4*)AGG);

    edge_kernel<<<E_TOT / 32, 256, 0, stream>>>(senders, (const float4*)AGG, (const float4*)V,
                                                Wlt, SCAL, out + (size_t)E_TOT * 512);

    const float s640 = 0.03952847075210474f;  // 1/sqrt(640)
    const float s512 = 0.044194173824159216f; // 1/sqrt(512)
    const int gemm_grid = (E_TOT / 256) * 2;  // 512 M-tiles x 2 N-tiles = 1024
    mlp_gemm<0><<<gemm_grid, 512, 0, stream>>>(XB, SCAL, W1t, 640, s640, nullptr, H1, nullptr);
    mlp_gemm<0><<<gemm_grid, 512, 0, stream>>>(H1, nullptr, W2t, 512, s512, nullptr, H2, nullptr);
    mlp_gemm<1><<<gemm_grid, 512, 0, stream>>>(H2, nullptr, W3t, 512, s512, ENV, nullptr, out);
}